// Round 11
// baseline (747.022 us; speedup 1.0000x reference)
//
#include <hip/hip_runtime.h>
#include <hip/hip_cooperative_groups.h>

namespace cg = cooperative_groups;

#define N_NODES 10000
#define N_EDGES 160000
#define TW 120        // per-node T row: [f=0..3 ea-weighted][f=4 bias part] x 24 ch
#define MAXGRID 1024

// Module-owned scratch (immune to d_ws poisoning). Fully rebuilt every call.
__device__ float  g_TA[N_NODES * TW];
__device__ float  g_TB[N_NODES * TW];
__device__ float  g_hA[N_NODES * 24];
__device__ float  g_hB[N_NODES * 24];
__device__ int    g_deg[N_NODES];
__device__ int    g_off[N_NODES + 1];
__device__ int    g_csr_src[N_EDGES];
__device__ float4 g_csr_ea[N_EDGES];
__device__ float  g_partial[MAXGRID * 16];

// Fused layer phase: node-parallel gather over CSR (one dependent load level:
// csr_src[k] -> T row), + root term + relu6, + optional next-layer T projection.
// Block: 256 threads, 240 active as (o=tid%24, y=tid/24) over 10 nodes.
template <int IN_C, bool HAS_NEXT>
__device__ __forceinline__ void layer_phase(
    const float* __restrict__ T_in, const float* __restrict__ h_in,
    const float* __restrict__ root, const float* __restrict__ bias,
    float* __restrict__ h_out, float* __restrict__ T_out,
    const float* __restrict__ sWt, float* __restrict__ smB, int tid) {
    float* sroot = smB;          // [IN_C*24]
    float* sbias = smB + 576;    // [24]
    float* shin  = smB + 600;    // [10][24] (stride 24, IN_C used)
    float* shh   = smB + 840;    // [10][24]
    for (int idx = tid; idx < IN_C * 24; idx += 256) sroot[idx] = root[idx];
    if (tid < 24) sbias[tid] = bias[tid];
    __syncthreads();
    const int o = tid % 24, y = tid / 24;
    for (int g = blockIdx.x; g < N_NODES / 10; g += gridDim.x) {
        const int n = g * 10 + y;
        if (tid < 240 && o < IN_C) shin[y * 24 + o] = h_in[n * IN_C + o];
        __syncthreads();
        if (tid < 240) {
            const int ks = g_off[n], ke = g_off[n + 1];
            float acc = -INFINITY;
#pragma unroll 4
            for (int k = ks; k < ke; ++k) {
                const int s = g_csr_src[k];
                const float4 a = g_csr_ea[k];
                const float* __restrict__ Tr = T_in + (size_t)s * TW;
                float m = Tr[96 + o];
                m = fmaf(a.x, Tr[o], m);
                m = fmaf(a.y, Tr[24 + o], m);
                m = fmaf(a.z, Tr[48 + o], m);
                m = fmaf(a.w, Tr[72 + o], m);
                acc = fmaxf(acc, m);
            }
            float r = sbias[o];
#pragma unroll
            for (int i = 0; i < IN_C; ++i) r = fmaf(shin[y * 24 + i], sroot[i * 24 + o], r);
            const float h = fminf(fmaxf(((ks == ke) ? 0.f : acc) + r, 0.f), 6.f);
            h_out[n * 24 + o] = h;
            if (HAS_NEXT) shh[y * 24 + o] = h;
        }
        __syncthreads();
        if (HAS_NEXT && tid < 240) {
#pragma unroll
            for (int f = 0; f < 5; ++f) {
                const int xx = f * 24 + o;
                float t = 0.f;
#pragma unroll
                for (int i = 0; i < 24; ++i) t = fmaf(shh[y * 24 + i], sWt[i * TW + xx], t);
                T_out[n * TW + xx] = t;
            }
        }
        __syncthreads();
    }
}

__global__ void __launch_bounds__(256)
mega_kernel(const float* __restrict__ x,     const float* __restrict__ ea,
            const int* __restrict__ src,     const int* __restrict__ dst,
            const float* __restrict__ few,   const float* __restrict__ feb,
            const float* __restrict__ ew,    const float* __restrict__ ebias,
            const float* __restrict__ root0, const float* __restrict__ bias0,
            const float* __restrict__ roots, const float* __restrict__ biases,
            const float* __restrict__ w1,    const float* __restrict__ b1,
            const float* __restrict__ w2,    const float* __restrict__ b2,
            float* __restrict__ out) {
    cg::grid_group grid = cg::this_grid();
    __shared__ float smA[24 * TW];   // shared edge-NN proj weights (persist)
    __shared__ float smB[4096];      // phase-local
    const int tid = threadIdx.x;
    const int bid = blockIdx.x;
    const int nb = gridDim.x;

    // ---- P0: stage sWt (ew/ebias transposed), few/feb; zero deg; tmat0 ----
    for (int idx = tid; idx < 24 * TW; idx += 256) {
        const int i = idx / TW, xx = idx - i * TW, f = xx / 24, oo = xx - f * 24;
        smA[idx] = (f < 4) ? ew[f * 576 + i * 24 + oo] : ebias[i * 24 + oo];
    }
    for (int idx = tid; idx < 8 * TW; idx += 256) {
        const int i = idx / TW, xx = idx - i * TW, f = xx / 24, oo = xx - f * 24;
        smB[idx] = (f < 4) ? few[f * 192 + i * 24 + oo] : feb[i * 24 + oo];
    }
    for (int idx = bid * 256 + tid; idx < N_NODES; idx += nb * 256) g_deg[idx] = 0;
    __syncthreads();
    {
        const int ln = tid / TW, xx = tid - ln * TW;  // tid<240: 2 nodes x 120
        for (int g = bid; g < N_NODES / 2; g += nb) {
            if (tid < 240) {
                const int n = g * 2 + ln;
                float acc = 0.f;
#pragma unroll
                for (int i = 0; i < 8; ++i) acc = fmaf(x[n * 8 + i], smB[i * TW + xx], acc);
                g_TA[n * TW + xx] = acc;
            }
        }
    }
    grid.sync();
    // ---- P1: degree histogram ----
    for (int e = bid * 256 + tid; e < N_EDGES; e += nb * 256)
        atomicAdd(&g_deg[dst[e]], 1);
    grid.sync();
    // ---- P2: exclusive scan (block 0; 256 thr x 40 items) ----
    if (bid == 0) {
        int* sI = (int*)smB;
        const int base = tid * 40;
        int tot = 0;
        for (int j = 0; j < 40; ++j) {
            const int idx = base + j;
            if (idx < N_NODES) tot += g_deg[idx];
        }
        sI[tid] = tot;
        __syncthreads();
        for (int off = 1; off < 256; off <<= 1) {
            const int t2 = (tid >= off) ? sI[tid - off] : 0;
            __syncthreads();
            sI[tid] += t2;
            __syncthreads();
        }
        int run = sI[tid] - tot;
        for (int j = 0; j < 40; ++j) {
            const int idx = base + j;
            if (idx < N_NODES) {
                const int d = g_deg[idx];
                g_off[idx] = run;
                g_deg[idx] = run;   // becomes scatter cursor
                run += d;
            }
        }
        if (tid == 0) g_off[N_NODES] = N_EDGES;
    }
    grid.sync();
    // ---- P3: scatter (materialize src+ea in CSR order) ----
    for (int e = bid * 256 + tid; e < N_EDGES; e += nb * 256) {
        const int d = dst[e];
        const int p = atomicAdd(&g_deg[d], 1);
        g_csr_src[p] = src[e];
        g_csr_ea[p] = ((const float4*)ea)[e];
    }
    grid.sync();
    // ---- 5 fused layers ----
    layer_phase<8, true>(g_TA, x, root0, bias0, g_hA, g_TB, smA, smB, tid);
    grid.sync();
    layer_phase<24, true>(g_TB, g_hA, roots + 0 * 576, biases + 0 * 24, g_hB, g_TA, smA, smB, tid);
    grid.sync();
    layer_phase<24, true>(g_TA, g_hB, roots + 1 * 576, biases + 1 * 24, g_hA, g_TB, smA, smB, tid);
    grid.sync();
    layer_phase<24, true>(g_TB, g_hA, roots + 2 * 576, biases + 2 * 24, g_hB, g_TA, smA, smB, tid);
    grid.sync();
    layer_phase<24, false>(g_TA, g_hB, roots + 3 * 576, biases + 3 * 24, g_hA, (float*)0, smA, smB, tid);
    grid.sync();
    // ---- head stage 1: per-block partials (all blocks, deterministic) ----
    {
        float acc[16];
#pragma unroll
        for (int j = 0; j < 16; ++j) acc[j] = 0.f;
        for (int k = bid * 256 + tid; k < N_NODES * 24; k += nb * 256) {
            const float f = g_hA[k];
            const float4* wp = (const float4*)(w1 + (size_t)k * 16);
#pragma unroll
            for (int q = 0; q < 4; ++q) {
                const float4 w = wp[q];
                acc[q * 4 + 0] = fmaf(f, w.x, acc[q * 4 + 0]);
                acc[q * 4 + 1] = fmaf(f, w.y, acc[q * 4 + 1]);
                acc[q * 4 + 2] = fmaf(f, w.z, acc[q * 4 + 2]);
                acc[q * 4 + 3] = fmaf(f, w.w, acc[q * 4 + 3]);
            }
        }
#pragma unroll
        for (int j = 0; j < 16; ++j) smB[tid * 16 + j] = acc[j];
        __syncthreads();
        for (int off = 128; off > 0; off >>= 1) {
            if (tid < off) {
#pragma unroll
                for (int j = 0; j < 16; ++j)
                    smB[tid * 16 + j] += smB[(tid + off) * 16 + j];
            }
            __syncthreads();
        }
        if (tid < 16) g_partial[bid * 16 + tid] = smB[tid];
    }
    grid.sync();
    // ---- head stage 2 (block 0; fixed-order reduce + ELU + dot + ELU) ----
    if (bid == 0) {
        const int j = tid & 15, seg = tid >> 4;  // 16 segs x 16 ch
        float s = 0.f;
        for (int p = seg; p < nb; p += 16) s += g_partial[p * 16 + j];
        smB[seg * 16 + j] = s;
        __syncthreads();
        if (tid < 16) {
            float a = b1[tid];
#pragma unroll
            for (int q = 0; q < 16; ++q) a += smB[q * 16 + tid];
            smB[256 + tid] = (a > 0.f) ? a : expm1f(a);
        }
        __syncthreads();
        if (tid == 0) {
            float a = b2[0];
#pragma unroll
            for (int q = 0; q < 16; ++q) a += smB[256 + q] * w2[q];
            out[0] = (a > 0.f) ? a : expm1f(a);
        }
    }
}

extern "C" void kernel_launch(void* const* d_in, const int* in_sizes, int n_in,
                              void* d_out, int out_size, void* d_ws, size_t ws_size,
                              hipStream_t stream) {
    const float* x      = (const float*)d_in[0];
    const float* ea     = (const float*)d_in[1];
    const int*   ei     = (const int*)d_in[2];
    const float* few    = (const float*)d_in[3];
    const float* feb    = (const float*)d_in[4];
    const float* ew     = (const float*)d_in[5];
    const float* ebias  = (const float*)d_in[6];
    const float* root0  = (const float*)d_in[7];
    const float* bias0  = (const float*)d_in[8];
    const float* roots  = (const float*)d_in[9];
    const float* biases = (const float*)d_in[10];
    const float* w1     = (const float*)d_in[11];
    const float* b1     = (const float*)d_in[12];
    const float* w2     = (const float*)d_in[13];
    const float* b2     = (const float*)d_in[14];
    float* out = (float*)d_out;

    const int* src = ei;
    const int* dst = ei + N_EDGES;

    // Size the cooperative grid to guaranteed co-residency (deterministic query).
    int maxBPC = 0;
    hipOccupancyMaxActiveBlocksPerMultiprocessor(&maxBPC, (const void*)mega_kernel, 256, 0);
    int grid = maxBPC * 256;               // 256 CUs on MI355X
    if (grid > MAXGRID) grid = MAXGRID;
    if (grid < 64) grid = 64;

    void* args[] = {&x, &ea, &src, &dst, &few, &feb, &ew, &ebias, &root0, &bias0,
                    &roots, &biases, &w1, &b1, &w2, &b2, &out};
    hipLaunchCooperativeKernel((const void*)mega_kernel, dim3(grid), dim3(256),
                               args, 0, stream);
}

// Round 12
// 321.504 us; speedup vs baseline: 2.3235x; 2.3235x over previous
//
#include <hip/hip_runtime.h>

#define N_NODES 10000
#define N_EDGES 160000
#define FNODE 8
#define C 24
#define HID 16
#define NB_HEAD 240
#define TW (5 * C)   // 120: per-node T row = [f=0..3 ea-weighted][f=4 bias part]

// Module-owned scratch (immune to d_ws poisoning; zero-initialized at load).
// Every call leaves g_deg zeroed and counters zeroed -> identical work per call.
__device__ float  g_TA[N_NODES * TW];
__device__ float  g_TB[N_NODES * TW];
__device__ float  g_hA[N_NODES * C];
__device__ float  g_hB[N_NODES * C];
__device__ int    g_deg[N_NODES];        // zero at call start; hist -> cursor -> re-zeroed
__device__ int    g_off[N_NODES + 1];
__device__ int    g_csr_src[N_EDGES];    // premultiplied: src * TW
__device__ float4 g_csr_ea[N_EDGES];
__device__ float  g_partial[NB_HEAD * HID];
__device__ int    g_cnt_hs;
__device__ int    g_cnt_sc;
__device__ int    g_cnt_hd;

// ---------- hist + (last block) scan ----------
__global__ void hist_scan_kernel(const int* __restrict__ dst) {
    __shared__ int sI[256];
    __shared__ int isLast;
    const int tid = threadIdx.x;
    const int e = blockIdx.x * 256 + tid;            // 625*256 == N_EDGES exact
    atomicAdd(&g_deg[dst[e]], 1);
    __threadfence();
    __syncthreads();
    if (tid == 0) isLast = (atomicAdd(&g_cnt_hs, 1) == (int)gridDim.x - 1);
    __syncthreads();
    if (!isLast) return;
    __threadfence();
    // exclusive scan of 10000 degrees: 256 threads x 40 items
    int v[40];
    int tot = 0;
    const int base = tid * 40;
#pragma unroll
    for (int j = 0; j < 40; ++j) {
        const int idx = base + j;
        v[j] = (idx < N_NODES) ? g_deg[idx] : 0;
        tot += v[j];
    }
    sI[tid] = tot;
    __syncthreads();
    for (int off = 1; off < 256; off <<= 1) {
        const int t2 = (tid >= off) ? sI[tid - off] : 0;
        __syncthreads();
        sI[tid] += t2;
        __syncthreads();
    }
    int run = sI[tid] - tot;
#pragma unroll
    for (int j = 0; j < 40; ++j) {
        const int idx = base + j;
        if (idx < N_NODES) { g_off[idx] = run; g_deg[idx] = run; run += v[j]; }
    }
    if (tid == 0) { g_off[N_NODES] = N_EDGES; g_cnt_hs = 0; }
}

// ---------- scatter (materialize src*TW + ea in CSR order) + (last block) re-zero deg ----------
__global__ void scatter_kernel(const int* __restrict__ src,
                               const int* __restrict__ dst,
                               const float* __restrict__ ea) {
    __shared__ int isLast;
    const int tid = threadIdx.x;
    const int e = blockIdx.x * 256 + tid;
    {
        const int d = dst[e];
        const int p = atomicAdd(&g_deg[d], 1);
        g_csr_src[p] = src[e] * TW;
        g_csr_ea[p] = ((const float4*)ea)[e];
    }
    __threadfence();
    __syncthreads();
    if (tid == 0) isLast = (atomicAdd(&g_cnt_sc, 1) == (int)gridDim.x - 1);
    __syncthreads();
    if (!isLast) return;
    for (int i = tid; i < N_NODES; i += 256) g_deg[i] = 0;   // clean for next call
    if (tid == 0) g_cnt_sc = 0;
}

// ---------- T projection for layer 0 (from x) ----------
template <int IN_C, int TNPB>
__global__ void tmat_kernel(const float* __restrict__ h,
                            const float* __restrict__ W,
                            const float* __restrict__ b,
                            float* __restrict__ T) {
    __shared__ float sW_t[IN_C * TW];
    __shared__ float sh[TNPB][IN_C];
    const int tid = threadIdx.x + threadIdx.y * TW;
    const int nthr = TW * TNPB;
    for (int idx = tid; idx < IN_C * TW; idx += nthr) {
        const int i = idx / TW;
        const int x = idx - i * TW;
        const int f = x / C;
        const int o = x - f * C;
        sW_t[idx] = (f < 4) ? W[f * IN_C * C + i * C + o] : b[i * C + o];
    }
    const int n = blockIdx.x * TNPB + threadIdx.y;
    if (threadIdx.x < IN_C) sh[threadIdx.y][threadIdx.x] = h[n * IN_C + threadIdx.x];
    __syncthreads();
    const int x = threadIdx.x;
    float acc = 0.f;
#pragma unroll
    for (int i = 0; i < IN_C; ++i)
        acc = fmaf(sh[threadIdx.y][i], sW_t[i * TW + x], acc);
    T[n * TW + x] = acc;
}

// ---------- Fused layer, 2-way edge split ----------
// Block (48, 8): 8 nodes; per node 24 channels x 2 half-lanes over alternate
// CSR edges (halves the serial dependent-load chain). LDS fmax combine
// (exact, order-invariant). Then root term + relu6 + optional next-T proj.
template <int IN_C, bool HAS_NEXT>
__global__ void __launch_bounds__(384)
layer2_kernel(const float* __restrict__ T_in,
              const float* __restrict__ h_in,
              const float* __restrict__ root,  // [IN_C][C]
              const float* __restrict__ bias,  // [C]
              const float* __restrict__ Wn,    // [4][C*C]
              const float* __restrict__ bn,    // [C*C]
              float* __restrict__ h_out,
              float* __restrict__ T_out) {
    __shared__ float sWt[HAS_NEXT ? C * TW : 1];
    __shared__ float sroot[IN_C * C];
    __shared__ float sbias[C];
    __shared__ float shin[8][IN_C];
    __shared__ float shh[8][C];
    __shared__ float sAcc[8][2][C];

    const int tx = threadIdx.x;          // 0..47
    const int y = threadIdx.y;           // 0..7
    const int half = tx / 24;
    const int o = tx - half * 24;
    const int tid = tx + 48 * y;         // 0..383

    if (HAS_NEXT) {
        for (int idx = tid; idx < C * TW; idx += 384) {
            const int i = idx / TW;
            const int xx = idx - i * TW;
            const int f = xx / C;
            const int oo = xx - f * C;
            sWt[idx] = (f < 4) ? Wn[f * C * C + i * C + oo] : bn[i * C + oo];
        }
    }
    for (int idx = tid; idx < IN_C * C; idx += 384) sroot[idx] = root[idx];
    if (tid < C) sbias[tid] = bias[tid];
    const int n = blockIdx.x * 8 + y;    // 1250*8 == N_NODES exact
    if (half == 0 && o < IN_C) shin[y][o] = h_in[n * IN_C + o];
    __syncthreads();

    const int ks = g_off[n];
    const int ke = g_off[n + 1];
    float acc = -INFINITY;
#pragma unroll 4
    for (int k = ks + half; k < ke; k += 2) {
        const int soff = g_csr_src[k];     // src*TW, broadcast within node group
        const float4 a = g_csr_ea[k];
        const float* __restrict__ Tr = T_in + soff;
        float m = Tr[4 * C + o];
        m = fmaf(a.x, Tr[0 * C + o], m);
        m = fmaf(a.y, Tr[1 * C + o], m);
        m = fmaf(a.z, Tr[2 * C + o], m);
        m = fmaf(a.w, Tr[3 * C + o], m);
        acc = fmaxf(acc, m);
    }
    sAcc[y][half][o] = acc;
    __syncthreads();
    if (half == 0) {
        const float a2 = fmaxf(acc, sAcc[y][1][o]);
        const float aggv = (ks == ke) ? 0.f : a2;
        float r = sbias[o];
#pragma unroll
        for (int i = 0; i < IN_C; ++i) r = fmaf(shin[y][i], sroot[i * C + o], r);
        const float h = fminf(fmaxf(aggv + r, 0.f), 6.f);
        h_out[n * C + o] = h;
        if (HAS_NEXT) shh[y][o] = h;
    }
    if (HAS_NEXT) {
        __syncthreads();
        for (int idx = tid; idx < 8 * TW; idx += 384) {
            const int ny = idx / TW;
            const int xx = idx - ny * TW;
            float t = 0.f;
#pragma unroll
            for (int i = 0; i < C; ++i) t = fmaf(shh[ny][i], sWt[i * TW + xx], t);
            T_out[(blockIdx.x * 8 + ny) * TW + xx] = t;
        }
    }
}

// ---------- Head: per-block partials + (last block) final reduce ----------
__global__ void head_kernel(const float* __restrict__ h,
                            const float* __restrict__ w1,
                            const float* __restrict__ b1,
                            const float* __restrict__ w2,
                            const float* __restrict__ b2,
                            float* __restrict__ out) {
    __shared__ float s[256 * HID];
    __shared__ int isLast;
    const int tid = threadIdx.x;
    float acc[HID];
#pragma unroll
    for (int j = 0; j < HID; ++j) acc[j] = 0.f;
    for (int k = blockIdx.x * 256 + tid; k < N_NODES * C; k += gridDim.x * 256) {
        const float f = h[k];
        const float4* wp = (const float4*)(w1 + (size_t)k * HID);
#pragma unroll
        for (int q = 0; q < 4; ++q) {
            const float4 w = wp[q];
            acc[q * 4 + 0] = fmaf(f, w.x, acc[q * 4 + 0]);
            acc[q * 4 + 1] = fmaf(f, w.y, acc[q * 4 + 1]);
            acc[q * 4 + 2] = fmaf(f, w.z, acc[q * 4 + 2]);
            acc[q * 4 + 3] = fmaf(f, w.w, acc[q * 4 + 3]);
        }
    }
#pragma unroll
    for (int j = 0; j < HID; ++j) s[tid * HID + j] = acc[j];
    __syncthreads();
    for (int off = 128; off > 0; off >>= 1) {
        if (tid < off) {
#pragma unroll
            for (int j = 0; j < HID; ++j)
                s[tid * HID + j] += s[(tid + off) * HID + j];
        }
        __syncthreads();
    }
    if (tid < HID) g_partial[blockIdx.x * HID + tid] = s[tid];
    __threadfence();
    __syncthreads();
    if (tid == 0) isLast = (atomicAdd(&g_cnt_hd, 1) == (int)gridDim.x - 1);
    __syncthreads();
    if (!isLast) return;
    __threadfence();
    if (tid < HID) {
        float a = b1[tid];
        for (int p = 0; p < (int)gridDim.x; ++p) a += g_partial[p * HID + tid];
        s[tid] = (a > 0.f) ? a : expm1f(a);
    }
    __syncthreads();
    if (tid == 0) {
        float a = b2[0];
#pragma unroll
        for (int q = 0; q < HID; ++q) a += s[q] * w2[q];
        out[0] = (a > 0.f) ? a : expm1f(a);
        g_cnt_hd = 0;
    }
}

extern "C" void kernel_launch(void* const* d_in, const int* in_sizes, int n_in,
                              void* d_out, int out_size, void* d_ws, size_t ws_size,
                              hipStream_t stream) {
    const float* x      = (const float*)d_in[0];
    const float* ea     = (const float*)d_in[1];
    const int*   ei     = (const int*)d_in[2];
    const float* few    = (const float*)d_in[3];
    const float* feb    = (const float*)d_in[4];
    const float* ew     = (const float*)d_in[5];
    const float* ebias  = (const float*)d_in[6];
    const float* root0  = (const float*)d_in[7];
    const float* bias0  = (const float*)d_in[8];
    const float* roots  = (const float*)d_in[9];
    const float* biases = (const float*)d_in[10];
    const float* w1     = (const float*)d_in[11];
    const float* b1     = (const float*)d_in[12];
    const float* w2     = (const float*)d_in[13];
    const float* b2     = (const float*)d_in[14];
    float* out = (float*)d_out;

    const int* src = ei;
    const int* dst = ei + N_EDGES;

    void *pTA_, *pTB_, *pA_, *pB_;
    hipGetSymbolAddress(&pTA_, HIP_SYMBOL(g_TA));
    hipGetSymbolAddress(&pTB_, HIP_SYMBOL(g_TB));
    hipGetSymbolAddress(&pA_,  HIP_SYMBOL(g_hA));
    hipGetSymbolAddress(&pB_,  HIP_SYMBOL(g_hB));
    float* TA = (float*)pTA_;
    float* TB = (float*)pTB_;
    float* hA = (float*)pA_;
    float* hB = (float*)pB_;

    hist_scan_kernel<<<N_EDGES / 256, 256, 0, stream>>>(dst);
    scatter_kernel<<<N_EDGES / 256, 256, 0, stream>>>(src, dst, ea);

    dim3 tblk(TW, 8);
    tmat_kernel<FNODE, 8><<<N_NODES / 8, tblk, 0, stream>>>(x, few, feb, TA);

    dim3 lblk(48, 8);
    const int lgrid = N_NODES / 8;   // 1250 exact
    layer2_kernel<FNODE, true><<<lgrid, lblk, 0, stream>>>(
        TA, x, root0, bias0, ew, ebias, hA, TB);
    layer2_kernel<C, true><<<lgrid, lblk, 0, stream>>>(
        TB, hA, roots + 0 * C * C, biases + 0 * C, ew, ebias, hB, TA);
    layer2_kernel<C, true><<<lgrid, lblk, 0, stream>>>(
        TA, hB, roots + 1 * C * C, biases + 1 * C, ew, ebias, hA, TB);
    layer2_kernel<C, true><<<lgrid, lblk, 0, stream>>>(
        TB, hA, roots + 2 * C * C, biases + 2 * C, ew, ebias, hB, TA);
    layer2_kernel<C, false><<<lgrid, lblk, 0, stream>>>(
        TA, hB, roots + 3 * C * C, biases + 3 * C, ew, ebias, hA, TB);

    head_kernel<<<NB_HEAD, 256, 0, stream>>>(hA, w1, b1, w2, b2, out);
}

// Round 13
// 155.149 us; speedup vs baseline: 4.8149x; 2.0722x over previous
//
#include <hip/hip_runtime.h>

#define N_NODES 10000
#define N_EDGES 160000
#define FNODE 8
#define C 24
#define HID 16
#define NB_HEAD 240
#define TW (5 * C)   // 120: per-node T row = [f=0..3 ea-weighted][f=4 bias part]

// Module-owned scratch (immune to d_ws poisoning). Fully rebuilt every call.
__device__ float  g_TA[N_NODES * TW];
__device__ float  g_TB[N_NODES * TW];
__device__ float  g_hA[N_NODES * C];
__device__ float  g_hB[N_NODES * C];
__device__ int    g_deg[N_NODES];        // zeroed each call, then hist, then cursor
__device__ int    g_off[N_NODES + 1];
__device__ int    g_csr_src[N_EDGES];    // premultiplied: src * TW
__device__ float4 g_csr_ea[N_EDGES];
__device__ float  g_partial[NB_HEAD * HID];

// ---------- CSR build (no device-scope fences anywhere) ----------
__global__ void csr_zero_kernel() {
    const int n = blockIdx.x * blockDim.x + threadIdx.x;
    if (n < N_NODES) g_deg[n] = 0;
}
__global__ void csr_hist_kernel(const int* __restrict__ dst) {
    const int e = blockIdx.x * blockDim.x + threadIdx.x;   // 625*256 exact
    atomicAdd(&g_deg[dst[e]], 1);
}
#define SCAN_T 1024
#define SCAN_I 10
__global__ void csr_scan_kernel() {
    __shared__ int s[SCAN_T];
    const int tid = threadIdx.x;
    const int base = tid * SCAN_I;
    int v[SCAN_I];
    int tot = 0;
#pragma unroll
    for (int j = 0; j < SCAN_I; ++j) {
        const int idx = base + j;
        v[j] = (idx < N_NODES) ? g_deg[idx] : 0;
        tot += v[j];
    }
    s[tid] = tot;
    __syncthreads();
    for (int off = 1; off < SCAN_T; off <<= 1) {
        const int t = (tid >= off) ? s[tid - off] : 0;
        __syncthreads();
        s[tid] += t;
        __syncthreads();
    }
    int run = s[tid] - tot;
#pragma unroll
    for (int j = 0; j < SCAN_I; ++j) {
        const int idx = base + j;
        if (idx < N_NODES) { g_off[idx] = run; g_deg[idx] = run; }  // deg -> cursor
        run += v[j];
    }
    if (tid == 0) g_off[N_NODES] = N_EDGES;
}
__global__ void csr_scatter_kernel(const int* __restrict__ src,
                                   const int* __restrict__ dst,
                                   const float* __restrict__ ea) {
    const int e = blockIdx.x * blockDim.x + threadIdx.x;   // 625*256 exact
    const int d = dst[e];
    const int p = atomicAdd(&g_deg[d], 1);
    g_csr_src[p] = src[e] * TW;
    g_csr_ea[p] = ((const float4*)ea)[e];
}

// ---------- T projection for layer 0 (from x) ----------
template <int IN_C, int TNPB>
__global__ void tmat_kernel(const float* __restrict__ h,
                            const float* __restrict__ W,
                            const float* __restrict__ b,
                            float* __restrict__ T) {
    __shared__ float sW_t[IN_C * TW];
    __shared__ float sh[TNPB][IN_C];
    const int tid = threadIdx.x + threadIdx.y * TW;
    const int nthr = TW * TNPB;
    for (int idx = tid; idx < IN_C * TW; idx += nthr) {
        const int i = idx / TW;
        const int x = idx - i * TW;
        const int f = x / C;
        const int o = x - f * C;
        sW_t[idx] = (f < 4) ? W[f * IN_C * C + i * C + o] : b[i * C + o];
    }
    const int n = blockIdx.x * TNPB + threadIdx.y;
    if (threadIdx.x < IN_C) sh[threadIdx.y][threadIdx.x] = h[n * IN_C + threadIdx.x];
    __syncthreads();
    const int x = threadIdx.x;
    float acc = 0.f;
#pragma unroll
    for (int i = 0; i < IN_C; ++i)
        acc = fmaf(sh[threadIdx.y][i], sW_t[i * TW + x], acc);
    T[n * TW + x] = acc;
}

// ---------- Fused layer, 2-way edge split ----------
// Block (48, 8): 8 nodes; per node 24 channels x 2 half-lanes over alternate
// CSR edges (halves the serial dependent-load chain). LDS fmax combine
// (exact, order-invariant). Then root term + relu6 + optional next-T proj.
template <int IN_C, bool HAS_NEXT>
__global__ void __launch_bounds__(384)
layer2_kernel(const float* __restrict__ T_in,
              const float* __restrict__ h_in,
              const float* __restrict__ root,  // [IN_C][C]
              const float* __restrict__ bias,  // [C]
              const float* __restrict__ Wn,    // [4][C*C]
              const float* __restrict__ bn,    // [C*C]
              float* __restrict__ h_out,
              float* __restrict__ T_out) {
    __shared__ float sWt[HAS_NEXT ? C * TW : 1];
    __shared__ float sroot[IN_C * C];
    __shared__ float sbias[C];
    __shared__ float shin[8][IN_C];
    __shared__ float shh[8][C];
    __shared__ float sAcc[8][2][C];

    const int tx = threadIdx.x;          // 0..47
    const int y = threadIdx.y;           // 0..7
    const int half = tx / 24;
    const int o = tx - half * 24;
    const int tid = tx + 48 * y;         // 0..383

    if (HAS_NEXT) {
        for (int idx = tid; idx < C * TW; idx += 384) {
            const int i = idx / TW;
            const int xx = idx - i * TW;
            const int f = xx / C;
            const int oo = xx - f * C;
            sWt[idx] = (f < 4) ? Wn[f * C * C + i * C + oo] : bn[i * C + oo];
        }
    }
    for (int idx = tid; idx < IN_C * C; idx += 384) sroot[idx] = root[idx];
    if (tid < C) sbias[tid] = bias[tid];
    const int n = blockIdx.x * 8 + y;    // 1250*8 == N_NODES exact
    if (half == 0 && o < IN_C) shin[y][o] = h_in[n * IN_C + o];
    __syncthreads();

    const int ks = g_off[n];
    const int ke = g_off[n + 1];
    float acc = -INFINITY;
#pragma unroll 4
    for (int k = ks + half; k < ke; k += 2) {
        const int soff = g_csr_src[k];     // src*TW
        const float4 a = g_csr_ea[k];
        const float* __restrict__ Tr = T_in + soff;
        float m = Tr[4 * C + o];
        m = fmaf(a.x, Tr[0 * C + o], m);
        m = fmaf(a.y, Tr[1 * C + o], m);
        m = fmaf(a.z, Tr[2 * C + o], m);
        m = fmaf(a.w, Tr[3 * C + o], m);
        acc = fmaxf(acc, m);
    }
    sAcc[y][half][o] = acc;
    __syncthreads();
    if (half == 0) {
        const float a2 = fmaxf(acc, sAcc[y][1][o]);
        const float aggv = (ks == ke) ? 0.f : a2;
        float r = sbias[o];
#pragma unroll
        for (int i = 0; i < IN_C; ++i) r = fmaf(shin[y][i], sroot[i * C + o], r);
        const float h = fminf(fmaxf(aggv + r, 0.f), 6.f);
        h_out[n * C + o] = h;
        if (HAS_NEXT) shh[y][o] = h;
    }
    if (HAS_NEXT) {
        __syncthreads();
        for (int idx = tid; idx < 8 * TW; idx += 384) {
            const int ny = idx / TW;
            const int xx = idx - ny * TW;
            float t = 0.f;
#pragma unroll
            for (int i = 0; i < C; ++i) t = fmaf(shh[ny][i], sWt[i * TW + xx], t);
            T_out[(blockIdx.x * 8 + ny) * TW + xx] = t;
        }
    }
}

// ---------- Output head (deterministic two-stage GEMV) ----------
__global__ void head1_kernel(const float* __restrict__ h,
                             const float* __restrict__ w1,
                             float* __restrict__ partial) {
    __shared__ float s[256 * HID];
    const int tid = threadIdx.x;
    float acc[HID];
#pragma unroll
    for (int j = 0; j < HID; ++j) acc[j] = 0.f;
    for (int k = blockIdx.x * 256 + tid; k < N_NODES * C; k += gridDim.x * 256) {
        const float f = h[k];
        const float4* wp = (const float4*)(w1 + (size_t)k * HID);
#pragma unroll
        for (int q = 0; q < 4; ++q) {
            const float4 w = wp[q];
            acc[q * 4 + 0] = fmaf(f, w.x, acc[q * 4 + 0]);
            acc[q * 4 + 1] = fmaf(f, w.y, acc[q * 4 + 1]);
            acc[q * 4 + 2] = fmaf(f, w.z, acc[q * 4 + 2]);
            acc[q * 4 + 3] = fmaf(f, w.w, acc[q * 4 + 3]);
        }
    }
#pragma unroll
    for (int j = 0; j < HID; ++j) s[tid * HID + j] = acc[j];
    __syncthreads();
    for (int off = 128; off > 0; off >>= 1) {
        if (tid < off) {
#pragma unroll
            for (int j = 0; j < HID; ++j)
                s[tid * HID + j] += s[(tid + off) * HID + j];
        }
        __syncthreads();
    }
    if (tid < HID) partial[blockIdx.x * HID + tid] = s[tid];
}

__global__ void head2_kernel(const float* __restrict__ partial,
                             const float* __restrict__ b1,
                             const float* __restrict__ w2,
                             const float* __restrict__ b2,
                             float* __restrict__ out) {
    __shared__ float hid[HID];
    const int j = threadIdx.x;
    if (j < HID) {
        float a = b1[j];
        for (int p = 0; p < NB_HEAD; ++p) a += partial[p * HID + j];
        hid[j] = (a > 0.f) ? a : expm1f(a);
    }
    __syncthreads();
    if (j == 0) {
        float a = b2[0];
#pragma unroll
        for (int q = 0; q < HID; ++q) a += hid[q] * w2[q];
        out[0] = (a > 0.f) ? a : expm1f(a);
    }
}

extern "C" void kernel_launch(void* const* d_in, const int* in_sizes, int n_in,
                              void* d_out, int out_size, void* d_ws, size_t ws_size,
                              hipStream_t stream) {
    const float* x      = (const float*)d_in[0];
    const float* ea     = (const float*)d_in[1];
    const int*   ei     = (const int*)d_in[2];
    const float* few    = (const float*)d_in[3];
    const float* feb    = (const float*)d_in[4];
    const float* ew     = (const float*)d_in[5];
    const float* ebias  = (const float*)d_in[6];
    const float* root0  = (const float*)d_in[7];
    const float* bias0  = (const float*)d_in[8];
    const float* roots  = (const float*)d_in[9];
    const float* biases = (const float*)d_in[10];
    const float* w1     = (const float*)d_in[11];
    const float* b1     = (const float*)d_in[12];
    const float* w2     = (const float*)d_in[13];
    const float* b2     = (const float*)d_in[14];
    float* out = (float*)d_out;

    const int* src = ei;
    const int* dst = ei + N_EDGES;

    void *pTA_, *pTB_, *pA_, *pB_, *pPart_;
    hipGetSymbolAddress(&pTA_, HIP_SYMBOL(g_TA));
    hipGetSymbolAddress(&pTB_, HIP_SYMBOL(g_TB));
    hipGetSymbolAddress(&pA_,  HIP_SYMBOL(g_hA));
    hipGetSymbolAddress(&pB_,  HIP_SYMBOL(g_hB));
    hipGetSymbolAddress(&pPart_, HIP_SYMBOL(g_partial));
    float* TA = (float*)pTA_;
    float* TB = (float*)pTB_;
    float* hA = (float*)pA_;
    float* hB = (float*)pB_;
    float* partial = (float*)pPart_;

    csr_zero_kernel<<<(N_NODES + 255) / 256, 256, 0, stream>>>();
    csr_hist_kernel<<<N_EDGES / 256, 256, 0, stream>>>(dst);
    csr_scan_kernel<<<1, SCAN_T, 0, stream>>>();
    csr_scatter_kernel<<<N_EDGES / 256, 256, 0, stream>>>(src, dst, ea);

    dim3 tblk(TW, 8);
    tmat_kernel<FNODE, 8><<<N_NODES / 8, tblk, 0, stream>>>(x, few, feb, TA);

    dim3 lblk(48, 8);
    const int lgrid = N_NODES / 8;   // 1250 exact
    layer2_kernel<FNODE, true><<<lgrid, lblk, 0, stream>>>(
        TA, x, root0, bias0, ew, ebias, hA, TB);
    layer2_kernel<C, true><<<lgrid, lblk, 0, stream>>>(
        TB, hA, roots + 0 * C * C, biases + 0 * C, ew, ebias, hB, TA);
    layer2_kernel<C, true><<<lgrid, lblk, 0, stream>>>(
        TA, hB, roots + 1 * C * C, biases + 1 * C, ew, ebias, hA, TB);
    layer2_kernel<C, true><<<lgrid, lblk, 0, stream>>>(
        TB, hA, roots + 2 * C * C, biases + 2 * C, ew, ebias, hB, TA);
    layer2_kernel<C, false><<<lgrid, lblk, 0, stream>>>(
        TA, hB, roots + 3 * C * C, biases + 3 * C, ew, ebias, hA, TB);

    head1_kernel<<<NB_HEAD, 256, 0, stream>>>(hA, w1, partial);
    head2_kernel<<<1, 64, 0, stream>>>(partial, b1, w2, b2, out);
}